// Round 4
// baseline (289.423 us; speedup 1.0000x reference)
//
#include <hip/hip_runtime.h>
#include <hip/hip_bf16.h>

#define NN 8192
#define EE 262144
#define IND 256
#define HIDD 256
#define LATD 128

typedef __attribute__((ext_vector_type(8))) short bf16x8;
typedef __attribute__((ext_vector_type(4))) float f32x4;

// ---------------- zero (kernel, not memset: graph-replay-safe) ----------------
__global__ void zero_k(int* __restrict__ p, int n) {
    int i = blockIdx.x * 256 + threadIdx.x;
    if (i < n) p[i] = 0;
}

// ---------------- CSR build ----------------
__global__ void count_deg_k(const int* __restrict__ ei, int* __restrict__ deg) {
    int e = blockIdx.x * 256 + threadIdx.x;
    if (e < EE) atomicAdd(&deg[ei[EE + e]], 1);
}

__global__ void scan_k(const int* __restrict__ deg, int* __restrict__ off,
                       float* __restrict__ inv_deg) {
    __shared__ int part[1024];
    int t = threadIdx.x;
    int base = t * 8;
    int local[8];
    int s = 0;
    for (int i = 0; i < 8; ++i) { local[i] = s; s += deg[base + i]; }
    part[t] = s;
    __syncthreads();
    for (int ofs = 1; ofs < 1024; ofs <<= 1) {
        int v = (t >= ofs) ? part[t - ofs] : 0;
        __syncthreads();
        part[t] += v;
        __syncthreads();
    }
    int prefix = (t == 0) ? 0 : part[t - 1];
    for (int i = 0; i < 8; ++i) {
        off[base + i] = prefix + local[i];
        int d = deg[base + i];
        inv_deg[base + i] = 1.0f / (float)max(d, 1);
    }
    if (t == 1023) off[NN] = prefix + s;
}

__global__ void fill_adj_k(const int* __restrict__ ei, const int* __restrict__ off,
                           int* __restrict__ cur, int* __restrict__ adj) {
    int e = blockIdx.x * 256 + threadIdx.x;
    if (e < EE) {
        int d = ei[EE + e];
        int p = atomicAdd(&cur[d], 1);
        adj[off[d] + p] = ei[e];
    }
}

// ---------------- weight transpose f32 -> bf16 [N,K] ----------------
__global__ void transpose_f2b_k(const float* __restrict__ W, __hip_bfloat16* __restrict__ Wt,
                                int K, int Nn) {
    int i = blockIdx.x * 256 + threadIdx.x;
    if (i < K * Nn) {
        int k = i / Nn, n = i % Nn;
        Wt[n * K + k] = __float2bfloat16(W[i]);
    }
}

// ---------------- mean aggregation (gather over CSR) ----------------
template <typename T>
__global__ void agg_mean_k(const T* __restrict__ in, const int* __restrict__ adj,
                           const int* __restrict__ off, const float* __restrict__ inv_deg,
                           __hip_bfloat16* __restrict__ out, int D) {
    int node = blockIdx.x;
    int d = threadIdx.x;  // blockDim.x == D == 256
    int s = off[node], e = off[node + 1];
    float sum = 0.f;
    for (int j = s; j < e; ++j) {
        int src = adj[j];
        sum += (float)in[(size_t)src * D + d];
    }
    out[(size_t)node * D + d] = __float2bfloat16(sum * inv_deg[node]);
}

// ---------------- MFMA GEMM:  C = act( sum_p A_p @ Bt_p^T + bias ) ----------------
// A1: [M,K] bf16.  A2: bf16 or f32 (A2F32).  Bt_p: [N,K] bf16 (B transposed).
// OUTMODE: 0 = f32 out, 1 = bf16 out, 2 = f32 out + bf16 secondary copy.
template <int NPAIRS, bool A2F32, bool RELU, bool BIAS, int OUTMODE>
__global__ __launch_bounds__(256) void mfma_gemm_k(
        const __hip_bfloat16* __restrict__ A1, const __hip_bfloat16* __restrict__ Bt1,
        const void* __restrict__ A2v, const __hip_bfloat16* __restrict__ Bt2,
        const float* __restrict__ bias, float* __restrict__ outF,
        __hip_bfloat16* __restrict__ outB, __hip_bfloat16* __restrict__ outB2,
        int N, int K) {
    int tid = threadIdx.x;
    int wid = tid >> 6, lane = tid & 63;
    int wm = wid >> 1, wn = wid & 1;
    int row0 = blockIdx.x * 128 + wm * 64;
    int col0 = blockIdx.y * 128 + wn * 64;
    int lrow = lane & 15;
    int lk = (lane >> 4) * 8;

    f32x4 acc[4][4] = {};

#pragma unroll
    for (int p = 0; p < NPAIRS; ++p) {
        const __hip_bfloat16* A = (p == 0) ? A1 : (const __hip_bfloat16*)A2v;
        const __hip_bfloat16* Bt = (p == 0) ? Bt1 : Bt2;
        for (int ks = 0; ks < K; ks += 32) {
            bf16x8 a[4], b[4];
            if (A2F32 && p == 1) {
                const float* Af = (const float*)A2v;
#pragma unroll
                for (int i = 0; i < 4; ++i) {
                    const float* src = Af + (size_t)(row0 + i * 16 + lrow) * K + ks + lk;
                    f32x4 lo = *reinterpret_cast<const f32x4*>(src);
                    f32x4 hi = *reinterpret_cast<const f32x4*>(src + 4);
                    union { bf16x8 v; __hip_bfloat16 h[8]; } u;
#pragma unroll
                    for (int j = 0; j < 4; ++j) {
                        u.h[j] = __float2bfloat16(lo[j]);
                        u.h[4 + j] = __float2bfloat16(hi[j]);
                    }
                    a[i] = u.v;
                }
            } else {
#pragma unroll
                for (int i = 0; i < 4; ++i)
                    a[i] = *reinterpret_cast<const bf16x8*>(
                        A + (size_t)(row0 + i * 16 + lrow) * K + ks + lk);
            }
#pragma unroll
            for (int i = 0; i < 4; ++i)
                b[i] = *reinterpret_cast<const bf16x8*>(
                    Bt + (size_t)(col0 + i * 16 + lrow) * K + ks + lk);
#pragma unroll
            for (int mi = 0; mi < 4; ++mi)
#pragma unroll
                for (int ni = 0; ni < 4; ++ni)
                    acc[mi][ni] = __builtin_amdgcn_mfma_f32_16x16x32_bf16(
                        a[mi], b[ni], acc[mi][ni], 0, 0, 0);
        }
    }

    // C/D layout: col = lane&15, row = (lane>>4)*4 + j   [measured m89/m91]
    int crow = (lane >> 4) * 4;
    int ccol = lane & 15;
#pragma unroll
    for (int mi = 0; mi < 4; ++mi)
#pragma unroll
        for (int ni = 0; ni < 4; ++ni) {
            int col = col0 + ni * 16 + ccol;
            float badd = BIAS ? bias[col] : 0.f;
#pragma unroll
            for (int j = 0; j < 4; ++j) {
                int row = row0 + mi * 16 + crow + j;
                float v = acc[mi][ni][j] + badd;
                if (RELU) v = fmaxf(v, 0.f);
                size_t idx = (size_t)row * N + col;
                if (OUTMODE == 0) {
                    outF[idx] = v;
                } else if (OUTMODE == 1) {
                    outB[idx] = __float2bfloat16(v);
                } else {
                    outF[idx] = v;
                    outB2[idx] = __float2bfloat16(v);
                }
            }
        }
}

// ---------------- Threefry-2x32, jax_threefry_partitionable scheme ----------------
// element i: counters (hi32(i), lo32(i)) = (0, i); output = bits0 ^ bits1.
__device__ __forceinline__ unsigned rotl32(unsigned x, int r) {
    return (x << r) | (x >> (32 - r));
}

#define TF_ROUND(r)        \
    {                      \
        x0 += x1;          \
        x1 = rotl32(x1, r);\
        x1 ^= x0;          \
    }

__device__ __forceinline__ float tf_normal(unsigned i) {
    const unsigned ks0 = 0u, ks1 = 42u, ks2 = 0u ^ 42u ^ 0x1BD11BDAu;
    unsigned x0 = 0u + ks0;
    unsigned x1 = i + ks1;
    TF_ROUND(13) TF_ROUND(15) TF_ROUND(26) TF_ROUND(6)
    x0 += ks1; x1 += ks2 + 1u;
    TF_ROUND(17) TF_ROUND(29) TF_ROUND(16) TF_ROUND(24)
    x0 += ks2; x1 += ks0 + 2u;
    TF_ROUND(13) TF_ROUND(15) TF_ROUND(26) TF_ROUND(6)
    x0 += ks0; x1 += ks1 + 3u;
    TF_ROUND(17) TF_ROUND(29) TF_ROUND(16) TF_ROUND(24)
    x0 += ks1; x1 += ks2 + 4u;
    TF_ROUND(13) TF_ROUND(15) TF_ROUND(26) TF_ROUND(6)
    x0 += ks2; x1 += ks0 + 5u;
    unsigned bits = x0 ^ x1;
    float f = __uint_as_float((bits >> 9) | 0x3f800000u) - 1.0f;  // [0,1)
    const float lo = -0.99999994f;                                // nextafter(-1,0)
    float u = fmaxf(f * 2.0f + lo, lo);
    return 1.41421356f * erfinvf(u);
}

// ---------------- reparameterize + row L2-normalize (reads ws copies only) ----------------
__global__ void reparam_norm_k(const __hip_bfloat16* __restrict__ mu_b,
                               const __hip_bfloat16* __restrict__ lv_b,
                               float* __restrict__ z_out, __hip_bfloat16* __restrict__ nz) {
    int row = blockIdx.x;
    int t = threadIdx.x;  // 64 threads = 1 wave
    size_t b = (size_t)row * LATD;
    int c0 = t, c1 = t + 64;
    float m0 = __bfloat162float(mu_b[b + c0]);
    float m1 = __bfloat162float(mu_b[b + c1]);
    float s0 = expf(0.5f * __bfloat162float(lv_b[b + c0]));
    float s1 = expf(0.5f * __bfloat162float(lv_b[b + c1]));
    float z0 = m0 + tf_normal((unsigned)(b + c0)) * s0;
    float z1 = m1 + tf_normal((unsigned)(b + c1)) * s1;
    float s = z0 * z0 + z1 * z1;
#pragma unroll
    for (int o = 32; o; o >>= 1) s += __shfl_xor(s, o);
    float inv = 1.0f / (sqrtf(s) + 1e-8f);
    z_out[b + c0] = z0;
    z_out[b + c1] = z1;
    nz[b + c0] = __float2bfloat16(z0 * inv);
    nz[b + c1] = __float2bfloat16(z1 * inv);
}

// ---------------- launch ----------------
extern "C" void kernel_launch(void* const* d_in, const int* in_sizes, int n_in,
                              void* d_out, int out_size, void* d_ws, size_t ws_size,
                              hipStream_t stream) {
    const float* x = (const float*)d_in[0];
    const int* ei = (const int*)d_in[1];  // int64 in reference -> int32 in harness
    const float* Wl1 = (const float*)d_in[2];
    const float* bl1 = (const float*)d_in[3];
    const float* Wr1 = (const float*)d_in[4];
    const float* Wl2 = (const float*)d_in[5];
    const float* bl2 = (const float*)d_in[6];
    const float* Wr2 = (const float*)d_in[7];
    const float* Wl3 = (const float*)d_in[8];
    const float* bl3 = (const float*)d_in[9];
    const float* Wr3 = (const float*)d_in[10];

    float* out = (float*)d_out;
    char* ws = (char*)d_ws;

    // output layout (floats): [recon | mu | logvar | z]
    const size_t MU_OFF = (size_t)NN * NN;
    const size_t LV_OFF = MU_OFF + (size_t)NN * LATD;
    const size_t Z_OFF = LV_OFF + (size_t)NN * LATD;

    // workspace layout (13.63 MiB total, lifetime-overlaid):
    //   [0,      32768) deg          (live: CSR build)
    //   [32768,  65536) cur
    //   [65536, 102400) off
    //   [102400,135168) inv_deg
    //   [135168,1183744) adj         (live until meanh done)
    //   [0,     2097152) nz          (OVERLAYS csr region; live reparam->recon; csr dead)
    //   [1183744,1708032) WT (Wl1T 128K, Wr1T 128K, Wl2T/Wr2T/Wl3T/Wr3T 64K each)
    //   [1708032,5902336) meanx 4MB  (live conv1); reused as mu_b 2MB + lv_b 2MB (conv2/3 -> reparam)
    //   [5902336,10096640) h_b 4MB
    //   [10096640,14290944) meanh 4MB
    int* deg = (int*)(ws + 0);
    int* cur = (int*)(ws + 32768);
    int* off = (int*)(ws + 65536);
    float* inv_deg = (float*)(ws + 102400);
    int* adj = (int*)(ws + 135168);
    __hip_bfloat16* nz = (__hip_bfloat16*)(ws + 0);
    __hip_bfloat16* Wl1T = (__hip_bfloat16*)(ws + 1183744);
    __hip_bfloat16* Wr1T = (__hip_bfloat16*)(ws + 1314816);
    __hip_bfloat16* Wl2T = (__hip_bfloat16*)(ws + 1445888);
    __hip_bfloat16* Wr2T = (__hip_bfloat16*)(ws + 1511424);
    __hip_bfloat16* Wl3T = (__hip_bfloat16*)(ws + 1576960);
    __hip_bfloat16* Wr3T = (__hip_bfloat16*)(ws + 1642496);
    __hip_bfloat16* meanx = (__hip_bfloat16*)(ws + 1708032);
    __hip_bfloat16* mu_b = (__hip_bfloat16*)(ws + 1708032);   // overlays meanx (dead)
    __hip_bfloat16* lv_b = (__hip_bfloat16*)(ws + 3805184);   // overlays meanx (dead)
    __hip_bfloat16* h_b = (__hip_bfloat16*)(ws + 5902336);
    __hip_bfloat16* meanh = (__hip_bfloat16*)(ws + 10096640);

    // 1. CSR build (deg+cur zeroed by kernel every call — nz overlay poisons them)
    zero_k<<<64, 256, 0, stream>>>(deg, 16384);
    count_deg_k<<<EE / 256, 256, 0, stream>>>(ei, deg);
    scan_k<<<1, 1024, 0, stream>>>(deg, off, inv_deg);
    fill_adj_k<<<EE / 256, 256, 0, stream>>>(ei, off, cur, adj);

    // 2. weight transposes
    transpose_f2b_k<<<(IND * HIDD) / 256, 256, 0, stream>>>(Wl1, Wl1T, IND, HIDD);
    transpose_f2b_k<<<(IND * HIDD) / 256, 256, 0, stream>>>(Wr1, Wr1T, IND, HIDD);
    transpose_f2b_k<<<(HIDD * LATD) / 256, 256, 0, stream>>>(Wl2, Wl2T, HIDD, LATD);
    transpose_f2b_k<<<(HIDD * LATD) / 256, 256, 0, stream>>>(Wr2, Wr2T, HIDD, LATD);
    transpose_f2b_k<<<(HIDD * LATD) / 256, 256, 0, stream>>>(Wl3, Wl3T, HIDD, LATD);
    transpose_f2b_k<<<(HIDD * LATD) / 256, 256, 0, stream>>>(Wr3, Wr3T, HIDD, LATD);

    // 3. conv1: h = relu(meanx@Wl1 + bl1 + x@Wr1) -> bf16 h_b  (x converted in-kernel)
    agg_mean_k<float><<<NN, 256, 0, stream>>>(x, adj, off, inv_deg, meanx, IND);
    mfma_gemm_k<2, true, true, true, 1><<<dim3(NN / 128, HIDD / 128), 256, 0, stream>>>(
        meanx, Wl1T, (const void*)x, Wr1T, bl1, nullptr, h_b, nullptr, HIDD, IND);

    // 4. conv2/conv3 share aggregated h; dual-write f32->d_out + bf16->ws
    agg_mean_k<__hip_bfloat16><<<NN, 256, 0, stream>>>(h_b, adj, off, inv_deg, meanh, HIDD);
    mfma_gemm_k<2, false, false, true, 2><<<dim3(NN / 128, 1), 256, 0, stream>>>(
        meanh, Wl2T, (const void*)h_b, Wr2T, bl2, out + MU_OFF, nullptr, mu_b, LATD, HIDD);
    mfma_gemm_k<2, false, false, true, 2><<<dim3(NN / 128, 1), 256, 0, stream>>>(
        meanh, Wl3T, (const void*)h_b, Wr3T, bl3, out + LV_OFF, nullptr, lv_b, LATD, HIDD);

    // 5. reparameterize + normalize (eps inlined; reads ws copies, never d_out)
    reparam_norm_k<<<NN, 64, 0, stream>>>(mu_b, lv_b, out + Z_OFF, nz);

    // 6. recon = nz @ nz^T  (bf16 MFMA, fp32 out)
    mfma_gemm_k<1, false, false, false, 0><<<dim3(NN / 128, NN / 128), 256, 0, stream>>>(
        nz, nz, nullptr, nullptr, nullptr, out, nullptr, nullptr, NN, LATD);
}

// Round 5
// 221.344 us; speedup vs baseline: 1.3076x; 1.3076x over previous
//
#include <hip/hip_runtime.h>
#include <hip/hip_bf16.h>

#define NN 8192
#define EE 262144
#define IND 256
#define HIDD 256
#define LATD 128

typedef __attribute__((ext_vector_type(8))) short bf16x8;
typedef __attribute__((ext_vector_type(4))) float f32x4;

__device__ __forceinline__ unsigned short bf16u(float f) {
    __hip_bfloat16 h = __float2bfloat16(f);
    return *reinterpret_cast<unsigned short*>(&h);
}

// ---- prep: zero deg/cur + x f32->bf16 + 6 weight transposes (one launch) ----
__global__ __launch_bounds__(256) void prep_k(
        const float* __restrict__ x, __hip_bfloat16* __restrict__ x_b,
        const float* __restrict__ Wl1, const float* __restrict__ Wr1,
        const float* __restrict__ Wl2, const float* __restrict__ Wr2,
        const float* __restrict__ Wl3, const float* __restrict__ Wr3,
        __hip_bfloat16* __restrict__ Wl1T, __hip_bfloat16* __restrict__ Wr1T,
        __hip_bfloat16* __restrict__ Wl2T, __hip_bfloat16* __restrict__ Wr2T,
        __hip_bfloat16* __restrict__ Wl3T, __hip_bfloat16* __restrict__ Wr3T,
        int* __restrict__ deg) {
    int gid = blockIdx.x * 256 + threadIdx.x;
    if (gid < 16384) deg[gid] = 0;  // deg[8192] + cur[8192] (contiguous)
    if (gid < 524288) {
        // x: 4 floats -> 4 bf16
        f32x4 v = reinterpret_cast<const f32x4*>(x)[gid];
        uint2 o;
        o.x = (unsigned)bf16u(v[0]) | ((unsigned)bf16u(v[1]) << 16);
        o.y = (unsigned)bf16u(v[2]) | ((unsigned)bf16u(v[3]) << 16);
        reinterpret_cast<uint2*>(x_b)[gid] = o;
    } else {
        int g2 = gid - 524288;  // [0, 262144)
        if (g2 < 131072) {      // Wl1 / Wr1: [256,256] -> [256,256]^T
            int i = g2 & 65535;
            const float* W = (g2 < 65536) ? Wl1 : Wr1;
            __hip_bfloat16* Wt = (g2 < 65536) ? Wl1T : Wr1T;
            int k = i >> 8, n = i & 255;
            Wt[n * 256 + k] = __float2bfloat16(W[i]);
        } else {                // Wl2/Wr2/Wl3/Wr3: [256,128] -> [128,256]^T
            int g3 = g2 - 131072;
            int w = g3 >> 15, i = g3 & 32767;
            const float* Ws[4] = {Wl2, Wr2, Wl3, Wr3};
            __hip_bfloat16* Wts[4] = {Wl2T, Wr2T, Wl3T, Wr3T};
            int k = i >> 7, n = i & 127;
            Wts[w][n * 256 + k] = __float2bfloat16(Ws[w][i]);
        }
    }
}

// ---------------- CSR build ----------------
__global__ void count_deg_k(const int* __restrict__ ei, int* __restrict__ deg) {
    int e = blockIdx.x * 256 + threadIdx.x;
    if (e < EE) atomicAdd(&deg[ei[EE + e]], 1);
}

__global__ void scan_k(const int* __restrict__ deg, int* __restrict__ off,
                       float* __restrict__ inv_deg) {
    __shared__ int part[1024];
    int t = threadIdx.x;
    int base = t * 8;
    int local[8];
    int s = 0;
    for (int i = 0; i < 8; ++i) { local[i] = s; s += deg[base + i]; }
    part[t] = s;
    __syncthreads();
    for (int ofs = 1; ofs < 1024; ofs <<= 1) {
        int v = (t >= ofs) ? part[t - ofs] : 0;
        __syncthreads();
        part[t] += v;
        __syncthreads();
    }
    int prefix = (t == 0) ? 0 : part[t - 1];
    for (int i = 0; i < 8; ++i) {
        off[base + i] = prefix + local[i];
        int d = deg[base + i];
        inv_deg[base + i] = 1.0f / (float)max(d, 1);
    }
    if (t == 1023) off[NN] = prefix + s;
}

__global__ void fill_adj_k(const int* __restrict__ ei, const int* __restrict__ off,
                           int* __restrict__ cur, int* __restrict__ adj) {
    int e = blockIdx.x * 256 + threadIdx.x;
    if (e < EE) {
        int d = ei[EE + e];
        int p = atomicAdd(&cur[d], 1);
        adj[off[d] + p] = ei[e];
    }
}

// ---- mean aggregation: 2 nodes/block, packed 2xbf16 loads, 4-edge unroll ----
__global__ __launch_bounds__(256) void agg_mean2_k(
        const __hip_bfloat16* __restrict__ in, const int* __restrict__ adj,
        const int* __restrict__ off, const float* __restrict__ inv_deg,
        __hip_bfloat16* __restrict__ out) {
    int node = blockIdx.x * 2 + (threadIdx.x >> 7);
    int dp = threadIdx.x & 127;  // dim pair: dims 2dp, 2dp+1
    const unsigned* inu = (const unsigned*)in;
    int s = off[node], e = off[node + 1];
    float a0 = 0.f, a1 = 0.f;
    int j = s;
    for (; j + 4 <= e; j += 4) {
        int n0 = adj[j], n1 = adj[j + 1], n2 = adj[j + 2], n3 = adj[j + 3];
        unsigned u0 = inu[(size_t)n0 * 128 + dp];
        unsigned u1 = inu[(size_t)n1 * 128 + dp];
        unsigned u2 = inu[(size_t)n2 * 128 + dp];
        unsigned u3 = inu[(size_t)n3 * 128 + dp];
        a0 += __uint_as_float(u0 << 16);
        a1 += __uint_as_float(u0 & 0xffff0000u);
        a0 += __uint_as_float(u1 << 16);
        a1 += __uint_as_float(u1 & 0xffff0000u);
        a0 += __uint_as_float(u2 << 16);
        a1 += __uint_as_float(u2 & 0xffff0000u);
        a0 += __uint_as_float(u3 << 16);
        a1 += __uint_as_float(u3 & 0xffff0000u);
    }
    for (; j < e; ++j) {
        unsigned u = inu[(size_t)adj[j] * 128 + dp];
        a0 += __uint_as_float(u << 16);
        a1 += __uint_as_float(u & 0xffff0000u);
    }
    float w = inv_deg[node];
    unsigned o = (unsigned)bf16u(a0 * w) | ((unsigned)bf16u(a1 * w) << 16);
    ((unsigned*)out)[(size_t)node * 128 + dp] = o;
}

// ---------------- MFMA GEMM:  C = act( sum_p A_p @ Bt_p^T + bias ) ----------------
// A_p: [M,K] bf16.  Bt_p: [N,K] bf16.  128x128 tile, 4 waves of 64x64.
// OUTMODE: 0 = f32 nontemporal out, 1 = bf16 out.
template <int NPAIRS, bool RELU, bool BIAS, int OUTMODE>
__global__ __launch_bounds__(256) void mfma_gemm_k(
        const __hip_bfloat16* __restrict__ A1, const __hip_bfloat16* __restrict__ Bt1,
        const __hip_bfloat16* __restrict__ A2, const __hip_bfloat16* __restrict__ Bt2,
        const float* __restrict__ bias, float* __restrict__ outF,
        __hip_bfloat16* __restrict__ outB, int N, int K) {
    int tid = threadIdx.x;
    int wid = tid >> 6, lane = tid & 63;
    int wm = wid >> 1, wn = wid & 1;
    int row0 = blockIdx.x * 128 + wm * 64;
    int col0 = blockIdx.y * 128 + wn * 64;
    int lrow = lane & 15;
    int lk = (lane >> 4) * 8;

    f32x4 acc[4][4] = {};

#pragma unroll
    for (int p = 0; p < NPAIRS; ++p) {
        const __hip_bfloat16* A = (p == 0) ? A1 : A2;
        const __hip_bfloat16* Bt = (p == 0) ? Bt1 : Bt2;
        for (int ks = 0; ks < K; ks += 32) {
            bf16x8 a[4], b[4];
#pragma unroll
            for (int i = 0; i < 4; ++i)
                a[i] = *reinterpret_cast<const bf16x8*>(
                    A + (size_t)(row0 + i * 16 + lrow) * K + ks + lk);
#pragma unroll
            for (int i = 0; i < 4; ++i)
                b[i] = *reinterpret_cast<const bf16x8*>(
                    Bt + (size_t)(col0 + i * 16 + lrow) * K + ks + lk);
#pragma unroll
            for (int mi = 0; mi < 4; ++mi)
#pragma unroll
                for (int ni = 0; ni < 4; ++ni)
                    acc[mi][ni] = __builtin_amdgcn_mfma_f32_16x16x32_bf16(
                        a[mi], b[ni], acc[mi][ni], 0, 0, 0);
        }
    }

    // C/D layout: col = lane&15, row = (lane>>4)*4 + j
    int crow = (lane >> 4) * 4;
    int ccol = lane & 15;
#pragma unroll
    for (int mi = 0; mi < 4; ++mi)
#pragma unroll
        for (int ni = 0; ni < 4; ++ni) {
            int col = col0 + ni * 16 + ccol;
            float badd = BIAS ? bias[col] : 0.f;
#pragma unroll
            for (int j = 0; j < 4; ++j) {
                int row = row0 + mi * 16 + crow + j;
                float v = acc[mi][ni][j] + badd;
                if (RELU) v = fmaxf(v, 0.f);
                size_t idx = (size_t)row * N + col;
                if (OUTMODE == 0)
                    __builtin_nontemporal_store(v, &outF[idx]);
                else
                    outB[idx] = __float2bfloat16(v);
            }
        }
}

// ---- conv2+conv3 fused (blockIdx.y selects mu vs logvar), dual f32+bf16 write ----
__global__ __launch_bounds__(256) void conv23_k(
        const __hip_bfloat16* __restrict__ meanh, const __hip_bfloat16* __restrict__ h_b,
        const __hip_bfloat16* __restrict__ Wl2T, const __hip_bfloat16* __restrict__ Wr2T,
        const float* __restrict__ bl2,
        const __hip_bfloat16* __restrict__ Wl3T, const __hip_bfloat16* __restrict__ Wr3T,
        const float* __restrict__ bl3,
        float* __restrict__ muF, __hip_bfloat16* __restrict__ muB,
        float* __restrict__ lvF, __hip_bfloat16* __restrict__ lvB) {
    bool is3 = blockIdx.y != 0;
    const __hip_bfloat16* WlT = is3 ? Wl3T : Wl2T;
    const __hip_bfloat16* WrT = is3 ? Wr3T : Wr2T;
    const float* bias = is3 ? bl3 : bl2;
    float* oF = is3 ? lvF : muF;
    __hip_bfloat16* oB = is3 ? lvB : muB;

    int tid = threadIdx.x;
    int wid = tid >> 6, lane = tid & 63;
    int wm = wid >> 1, wn = wid & 1;
    int row0 = blockIdx.x * 128 + wm * 64;
    int col0 = wn * 64;  // N = 128
    int lrow = lane & 15;
    int lk = (lane >> 4) * 8;

    f32x4 acc[4][4] = {};

#pragma unroll
    for (int p = 0; p < 2; ++p) {
        const __hip_bfloat16* A = (p == 0) ? meanh : h_b;
        const __hip_bfloat16* Bt = (p == 0) ? WlT : WrT;
        for (int ks = 0; ks < HIDD; ks += 32) {
            bf16x8 a[4], b[4];
#pragma unroll
            for (int i = 0; i < 4; ++i)
                a[i] = *reinterpret_cast<const bf16x8*>(
                    A + (size_t)(row0 + i * 16 + lrow) * HIDD + ks + lk);
#pragma unroll
            for (int i = 0; i < 4; ++i)
                b[i] = *reinterpret_cast<const bf16x8*>(
                    Bt + (size_t)(col0 + i * 16 + lrow) * HIDD + ks + lk);
#pragma unroll
            for (int mi = 0; mi < 4; ++mi)
#pragma unroll
                for (int ni = 0; ni < 4; ++ni)
                    acc[mi][ni] = __builtin_amdgcn_mfma_f32_16x16x32_bf16(
                        a[mi], b[ni], acc[mi][ni], 0, 0, 0);
        }
    }

    int crow = (lane >> 4) * 4;
    int ccol = lane & 15;
#pragma unroll
    for (int mi = 0; mi < 4; ++mi)
#pragma unroll
        for (int ni = 0; ni < 4; ++ni) {
            int col = col0 + ni * 16 + ccol;
            float badd = bias[col];
#pragma unroll
            for (int j = 0; j < 4; ++j) {
                int row = row0 + mi * 16 + crow + j;
                float v = acc[mi][ni][j] + badd;
                size_t idx = (size_t)row * LATD + col;
                oF[idx] = v;
                oB[idx] = __float2bfloat16(v);
            }
        }
}

// ---------------- Threefry-2x32, jax_threefry_partitionable ----------------
__device__ __forceinline__ unsigned rotl32(unsigned x, int r) {
    return (x << r) | (x >> (32 - r));
}

#define TF_ROUND(r)        \
    {                      \
        x0 += x1;          \
        x1 = rotl32(x1, r);\
        x1 ^= x0;          \
    }

__device__ __forceinline__ float tf_normal(unsigned i) {
    const unsigned ks0 = 0u, ks1 = 42u, ks2 = 0u ^ 42u ^ 0x1BD11BDAu;
    unsigned x0 = 0u + ks0;
    unsigned x1 = i + ks1;
    TF_ROUND(13) TF_ROUND(15) TF_ROUND(26) TF_ROUND(6)
    x0 += ks1; x1 += ks2 + 1u;
    TF_ROUND(17) TF_ROUND(29) TF_ROUND(16) TF_ROUND(24)
    x0 += ks2; x1 += ks0 + 2u;
    TF_ROUND(13) TF_ROUND(15) TF_ROUND(26) TF_ROUND(6)
    x0 += ks0; x1 += ks1 + 3u;
    TF_ROUND(17) TF_ROUND(29) TF_ROUND(16) TF_ROUND(24)
    x0 += ks1; x1 += ks2 + 4u;
    TF_ROUND(13) TF_ROUND(15) TF_ROUND(26) TF_ROUND(6)
    x0 += ks2; x1 += ks0 + 5u;
    unsigned bits = x0 ^ x1;
    float f = __uint_as_float((bits >> 9) | 0x3f800000u) - 1.0f;  // [0,1)
    const float lo = -0.99999994f;                                // nextafter(-1,0)
    float u = fmaxf(f * 2.0f + lo, lo);
    return 1.41421356f * erfinvf(u);
}

// ---------------- reparameterize + row L2-normalize ----------------
__global__ void reparam_norm_k(const __hip_bfloat16* __restrict__ mu_b,
                               const __hip_bfloat16* __restrict__ lv_b,
                               float* __restrict__ z_out, __hip_bfloat16* __restrict__ nz) {
    int row = blockIdx.x;
    int t = threadIdx.x;  // 64 threads = 1 wave
    size_t b = (size_t)row * LATD;
    int c0 = t, c1 = t + 64;
    float m0 = __bfloat162float(mu_b[b + c0]);
    float m1 = __bfloat162float(mu_b[b + c1]);
    float s0 = expf(0.5f * __bfloat162float(lv_b[b + c0]));
    float s1 = expf(0.5f * __bfloat162float(lv_b[b + c1]));
    float z0 = m0 + tf_normal((unsigned)(b + c0)) * s0;
    float z1 = m1 + tf_normal((unsigned)(b + c1)) * s1;
    float s = z0 * z0 + z1 * z1;
#pragma unroll
    for (int o = 32; o; o >>= 1) s += __shfl_xor(s, o);
    float inv = 1.0f / (sqrtf(s) + 1e-8f);
    z_out[b + c0] = z0;
    z_out[b + c1] = z1;
    nz[b + c0] = __float2bfloat16(z0 * inv);
    nz[b + c1] = __float2bfloat16(z1 * inv);
}

// ---------------- launch ----------------
extern "C" void kernel_launch(void* const* d_in, const int* in_sizes, int n_in,
                              void* d_out, int out_size, void* d_ws, size_t ws_size,
                              hipStream_t stream) {
    const float* x = (const float*)d_in[0];
    const int* ei = (const int*)d_in[1];  // int64 in reference -> int32 in harness
    const float* Wl1 = (const float*)d_in[2];
    const float* bl1 = (const float*)d_in[3];
    const float* Wr1 = (const float*)d_in[4];
    const float* Wl2 = (const float*)d_in[5];
    const float* bl2 = (const float*)d_in[6];
    const float* Wr2 = (const float*)d_in[7];
    const float* Wl3 = (const float*)d_in[8];
    const float* bl3 = (const float*)d_in[9];
    const float* Wr3 = (const float*)d_in[10];

    float* out = (float*)d_out;
    char* ws = (char*)d_ws;

    // output layout (floats): [recon | mu | logvar | z]
    const size_t MU_OFF = (size_t)NN * NN;
    const size_t LV_OFF = MU_OFF + (size_t)NN * LATD;
    const size_t Z_OFF = LV_OFF + (size_t)NN * LATD;

    // workspace layout — fully disjoint except safe lifetime overlays (20.6 MB):
    //   [0,        1183744) CSR: deg 32K | cur 32K | off 36K | inv_deg 32K | adj 1M
    //   [1183744,  1708032) WT: Wl1T 128K | Wr1T 128K | Wl2T/Wr2T/Wl3T/Wr3T 64K each
    //   [1708032,  5902336) x_b 4MB
    //   [5902336, 10096640) meanx 4MB  -> overlaid by mu_b 2MB + lv_b 2MB after conv1
    //   [10096640,14290944) h_b 4MB
    //   [14290944,18485248) meanh 4MB
    //   [18485248,20582400) nz 2MB     (disjoint — no overlap with mu_b/lv_b)
    int* deg = (int*)(ws + 0);
    int* cur = (int*)(ws + 32768);
    int* off = (int*)(ws + 65536);
    float* inv_deg = (float*)(ws + 102400);
    int* adj = (int*)(ws + 135168);
    __hip_bfloat16* Wl1T = (__hip_bfloat16*)(ws + 1183744);
    __hip_bfloat16* Wr1T = (__hip_bfloat16*)(ws + 1314816);
    __hip_bfloat16* Wl2T = (__hip_bfloat16*)(ws + 1445888);
    __hip_bfloat16* Wr2T = (__hip_bfloat16*)(ws + 1511424);
    __hip_bfloat16* Wl3T = (__hip_bfloat16*)(ws + 1576960);
    __hip_bfloat16* Wr3T = (__hip_bfloat16*)(ws + 1642496);
    __hip_bfloat16* x_b = (__hip_bfloat16*)(ws + 1708032);
    __hip_bfloat16* meanx = (__hip_bfloat16*)(ws + 5902336);
    __hip_bfloat16* mu_b = (__hip_bfloat16*)(ws + 5902336);   // overlays meanx (dead)
    __hip_bfloat16* lv_b = (__hip_bfloat16*)(ws + 7999488);   // overlays meanx (dead)
    __hip_bfloat16* h_b = (__hip_bfloat16*)(ws + 10096640);
    __hip_bfloat16* meanh = (__hip_bfloat16*)(ws + 14290944);
    __hip_bfloat16* nz = (__hip_bfloat16*)(ws + 18485248);

    // 1. prep: zero deg/cur + x->bf16 + weight transposes
    prep_k<<<3072, 256, 0, stream>>>(x, x_b, Wl1, Wr1, Wl2, Wr2, Wl3, Wr3,
                                     Wl1T, Wr1T, Wl2T, Wr2T, Wl3T, Wr3T, deg);

    // 2. CSR build
    count_deg_k<<<EE / 256, 256, 0, stream>>>(ei, deg);
    scan_k<<<1, 1024, 0, stream>>>(deg, off, inv_deg);
    fill_adj_k<<<EE / 256, 256, 0, stream>>>(ei, off, cur, adj);

    // 3. conv1: h = relu(meanx@Wl1 + bl1 + x@Wr1) -> bf16 h_b
    agg_mean2_k<<<NN / 2, 256, 0, stream>>>(x_b, adj, off, inv_deg, meanx);
    mfma_gemm_k<2, true, true, 1><<<dim3(NN / 128, HIDD / 128), 256, 0, stream>>>(
        meanx, Wl1T, x_b, Wr1T, bl1, nullptr, h_b, HIDD, IND);

    // 4. conv2+conv3 fused (share meanh/h_b); dual-write f32->d_out + bf16->ws
    agg_mean2_k<<<NN / 2, 256, 0, stream>>>(h_b, adj, off, inv_deg, meanh);
    conv23_k<<<dim3(NN / 128, 2), 256, 0, stream>>>(
        meanh, h_b, Wl2T, Wr2T, bl2, Wl3T, Wr3T, bl3,
        out + MU_OFF, mu_b, out + LV_OFF, lv_b);

    // 5. reparameterize + normalize (Threefry inlined; reads ws copies only)
    reparam_norm_k<<<NN, 64, 0, stream>>>(mu_b, lv_b, out + Z_OFF, nz);

    // 6. recon = nz @ nz^T (bf16 MFMA, fp32 nontemporal out)
    mfma_gemm_k<1, false, false, 0><<<dim3(NN / 128, NN / 128), 256, 0, stream>>>(
        nz, nz, nullptr, nullptr, nullptr, out, nullptr, NN, LATD);
}